// Round 1
// baseline (750.845 us; speedup 1.0000x reference)
//
#include <hip/hip_runtime.h>
#include <hip/hip_bf16.h>
#include <stdint.h>

#define STATE 512
#define PROJ 300
#define PPAD 320
#define BATSEQ 320
#define TE 327680            // 320*1024 edges

typedef __bf16 bf16x8 __attribute__((ext_vector_type(8)));
typedef float f32x4 __attribute__((ext_vector_type(4)));

__device__ inline unsigned short f2bf(float x) {
  unsigned u = __builtin_bit_cast(unsigned, x);
  unsigned r = u + 0x7fffu + ((u >> 16) & 1u);   // round-to-nearest-even
  return (unsigned short)(r >> 16);
}
__device__ inline float bf2f(unsigned short h) {
  unsigned u = ((unsigned)h) << 16;
  return __builtin_bit_cast(float, u);
}

// ---------------- prep: pack W1/W2/W3 into MFMA B-fragment layout (bf16, P padded to 320),
// and pad biases to 320 floats ----------------
__global__ __launch_bounds__(256) void prep_kernel(
    const float* __restrict__ W1, const float* __restrict__ b1,
    const float* __restrict__ W2, const float* __restrict__ b2,
    const float* __restrict__ W3, const float* __restrict__ b3,
    unsigned short* __restrict__ w1p, unsigned short* __restrict__ w2p,
    unsigned short* __restrict__ w3p,
    float* __restrict__ b1p, float* __restrict__ b2p, float* __restrict__ b3p)
{
  int idx = blockIdx.x * 256 + threadIdx.x;
  const int WN = PPAD * STATE;                    // 163840
  if (idx < 3 * WN) {
    int which = idx / WN, r = idx % WN;
    int cs = r / 512, q = r % 512;                // cs = c*16+s
    int lane = q / 8, i = q % 8;
    int c = cs / 16, s = cs % 16;
    int p = c * 16 + (lane & 15);
    int k = s * 32 + (lane >> 4) * 8 + i;
    const float* W = (which == 0) ? W1 : ((which == 1) ? W2 : W3);
    unsigned short* dst = (which == 0) ? w1p : ((which == 1) ? w2p : w3p);
    float v = (p < PROJ) ? W[(size_t)p * STATE + k] : 0.0f;
    dst[r] = f2bf(v);
  } else if (idx < 3 * WN + 3 * PPAD) {
    int r = idx - 3 * WN;
    int which = r / PPAD, p = r % PPAD;
    const float* B = (which == 0) ? b1 : ((which == 1) ? b2 : b3);
    float* dst = (which == 0) ? b1p : ((which == 1) ? b2p : b3p);
    dst[p] = (p < PROJ) ? B[p] : 0.0f;
  }
}

// ---------------- edge kernel: stream edges once.
// per block: 64 rows (one b, two i-values, all j) -> LDS bf16 (XOR-swizzled).
//  - esumI[b][i][:]  (exclusive store), esumJ[b][j][:] (atomicAdd)
//  - sum over p of (edges . w2_p)^2 via 16x16x32 bf16 MFMA, per-wave partial
__global__ __launch_bounds__(256, 2) void edge_kernel(
    const float* __restrict__ edges, const unsigned short* __restrict__ w2p,
    float* __restrict__ esumI, float* __restrict__ esumJ,
    double* __restrict__ pedge)
{
  __shared__ __align__(16) unsigned short tile[64 * 512];   // 64 KiB
  const int tid = threadIdx.x;
  const int wave = tid >> 6, lane = tid & 63;
  const int blk = blockIdx.x;
  const float* src = edges + (size_t)blk * 64 * STATE;

  // stage 64x512 f32 -> bf16, swizzle: byte ^= (row&7)<<4
  #pragma unroll
  for (int m = 0; m < 32; ++m) {
    int k = wave + 4 * m;
    int row = k >> 1;
    int fc = (k & 1) * 64 + lane;                 // float4 column 0..127
    f32x4 v = *(const f32x4*)(src + row * STATE + fc * 4);
    unsigned lo = f2bf(v.x) | ((unsigned)f2bf(v.y) << 16);
    unsigned hi = f2bf(v.z) | ((unsigned)f2bf(v.w) << 16);
    unsigned long long pk = (unsigned long long)lo | ((unsigned long long)hi << 32);
    unsigned off = (unsigned)(row * 1024 + fc * 8) ^ (unsigned)((row & 7) << 4);
    *(unsigned long long*)((char*)tile + off) = pk;
  }
  __syncthreads();

  // ---- edge sums ----
  const int b = blk >> 4;                 // 16 blocks per b
  const int i0 = (blk & 15) * 2;
  for (int t = tid; t < 32 * 256; t += 256) {     // esumJ: 32 j x 256 d-pairs
    int j = t >> 8, dp = t & 255;
    unsigned o1 = (unsigned)(j * 1024 + dp * 4) ^ (unsigned)((j & 7) << 4);
    unsigned o2 = (unsigned)((j + 32) * 1024 + dp * 4) ^ (unsigned)((j & 7) << 4);
    unsigned p1 = *(const unsigned*)((const char*)tile + o1);
    unsigned p2 = *(const unsigned*)((const char*)tile + o2);
    float lo = bf2f((unsigned short)p1) + bf2f((unsigned short)p2);
    float hi = bf2f((unsigned short)(p1 >> 16)) + bf2f((unsigned short)(p2 >> 16));
    float* dst = esumJ + ((size_t)b * 32 + j) * STATE + dp * 2;
    atomicAdd(dst, lo);
    atomicAdd(dst + 1, hi);
  }
  for (int t = tid; t < 2 * 256; t += 256) {      // esumI: 2 i x 256 d-pairs
    int il = t >> 8, dp = t & 255;
    float lo = 0.f, hi = 0.f;
    for (int j = 0; j < 32; ++j) {
      int row = il * 32 + j;
      unsigned o = (unsigned)(row * 1024 + dp * 4) ^ (unsigned)((row & 7) << 4);
      unsigned p = *(const unsigned*)((const char*)tile + o);
      lo += bf2f((unsigned short)p);
      hi += bf2f((unsigned short)(p >> 16));
    }
    float* dst = esumI + ((size_t)b * 32 + i0 + il) * STATE + dp * 2;
    dst[0] = lo; dst[1] = hi;
  }

  // ---- MFMA: 64 rows x 320 cols (wave w owns cols w*80..+80), K=512 ----
  f32x4 acc[4][5];
  #pragma unroll
  for (int rg = 0; rg < 4; ++rg)
    #pragma unroll
    for (int c = 0; c < 5; ++c) { acc[rg][c][0]=0.f; acc[rg][c][1]=0.f; acc[rg][c][2]=0.f; acc[rg][c][3]=0.f; }
  const int lrow = lane & 15, lk = lane >> 4;
  const int cb = wave * 5;
  for (int s = 0; s < 16; ++s) {
    bf16x8 a[4];
    #pragma unroll
    for (int rg = 0; rg < 4; ++rg) {
      int row = rg * 16 + lrow;
      unsigned off = (unsigned)(row * 1024 + s * 64 + lk * 16) ^ (unsigned)((row & 7) << 4);
      a[rg] = *(const bf16x8*)((const char*)tile + off);
    }
    #pragma unroll
    for (int c = 0; c < 5; ++c) {
      int ch = cb + c;
      bf16x8 bfr = *(const bf16x8*)(w2p + ((size_t)((ch * 16 + s) * 64 + lane)) * 8);
      #pragma unroll
      for (int rg = 0; rg < 4; ++rg)
        acc[rg][c] = __builtin_amdgcn_mfma_f32_16x16x32_bf16(a[rg], bfr, acc[rg][c], 0, 0, 0);
    }
  }
  float ss = 0.f;
  #pragma unroll
  for (int rg = 0; rg < 4; ++rg)
    #pragma unroll
    for (int c = 0; c < 5; ++c)
      #pragma unroll
      for (int r = 0; r < 4; ++r) ss += acc[rg][c][r] * acc[rg][c][r];
  #pragma unroll
  for (int m = 32; m >= 1; m >>= 1) ss += __shfl_xor(ss, m, 64);
  if (lane == 0) pedge[(size_t)blk * 4 + wave] = (double)ss;
}

// ---------------- node kernel: one block per b (32 rows). Three staged phases:
// nodes -> f1,f3 ; esumI -> u2i ; esumJ -> u2j. Accumulates all scalar terms.
__global__ __launch_bounds__(256, 2) void node_kernel(
    const float* __restrict__ nodes, const float* __restrict__ esumI,
    const float* __restrict__ esumJ,
    const unsigned short* __restrict__ w1p, const unsigned short* __restrict__ w2p,
    const unsigned short* __restrict__ w3p,
    const float* __restrict__ b1p, const float* __restrict__ b2p,
    const float* __restrict__ b3p, double* __restrict__ pnode)
{
  __shared__ __align__(16) unsigned short tile[32 * 512];   // 32 KiB
  __shared__ float F3s[PPAD], F1s[PPAD];
  __shared__ double red[4][7];
  const int tid = threadIdx.x;
  const int wave = tid >> 6, lane = tid & 63;
  const int b = blockIdx.x;
  const size_t base = (size_t)b * 32 * STATE;

  for (int t = tid; t < PPAD; t += 256) { F3s[t] = 0.f; F1s[t] = 0.f; }

  const int lrow = lane & 15, lk = lane >> 4;
  const int cbase = wave * 5;

  auto stage = [&](const float* src) {
    #pragma unroll
    for (int m = 0; m < 16; ++m) {
      int k = wave + 4 * m;
      int row = k >> 1;
      int fc = (k & 1) * 64 + lane;
      f32x4 v = *(const f32x4*)(src + row * STATE + fc * 4);
      unsigned lo = f2bf(v.x) | ((unsigned)f2bf(v.y) << 16);
      unsigned hi = f2bf(v.z) | ((unsigned)f2bf(v.w) << 16);
      unsigned long long pk = (unsigned long long)lo | ((unsigned long long)hi << 32);
      unsigned off = (unsigned)(row * 1024 + fc * 8) ^ (unsigned)((row & 7) << 4);
      *(unsigned long long*)((char*)tile + off) = pk;
    }
  };
  auto aload = [&](int rg, int s) -> bf16x8 {
    int row = rg * 16 + lrow;
    unsigned off = (unsigned)(row * 1024 + s * 64 + lk * 16) ^ (unsigned)((row & 7) << 4);
    return *(const bf16x8*)((const char*)tile + off);
  };

  // ---- phase 1: f1, f3 ----
  stage(nodes + base);
  __syncthreads();
  f32x4 af1[2][5], af3[2][5];
  #pragma unroll
  for (int rg = 0; rg < 2; ++rg)
    #pragma unroll
    for (int c = 0; c < 5; ++c) {
      af1[rg][c][0]=0.f; af1[rg][c][1]=0.f; af1[rg][c][2]=0.f; af1[rg][c][3]=0.f;
      af3[rg][c][0]=0.f; af3[rg][c][1]=0.f; af3[rg][c][2]=0.f; af3[rg][c][3]=0.f;
    }
  for (int s = 0; s < 16; ++s) {
    bf16x8 a[2];
    #pragma unroll
    for (int rg = 0; rg < 2; ++rg) a[rg] = aload(rg, s);
    #pragma unroll
    for (int c = 0; c < 5; ++c) {
      size_t fo = ((size_t)(((cbase + c) * 16 + s) * 64 + lane)) * 8;
      bf16x8 bf1 = *(const bf16x8*)(w1p + fo);
      bf16x8 bf3 = *(const bf16x8*)(w3p + fo);
      #pragma unroll
      for (int rg = 0; rg < 2; ++rg) {
        af1[rg][c] = __builtin_amdgcn_mfma_f32_16x16x32_bf16(a[rg], bf1, af1[rg][c], 0, 0, 0);
        af3[rg][c] = __builtin_amdgcn_mfma_f32_16x16x32_bf16(a[rg], bf3, af3[rg][c], 0, 0, 0);
      }
    }
  }
  float s1 = 0.f, s3 = 0.f, s5 = 0.f;
  #pragma unroll
  for (int rg = 0; rg < 2; ++rg)
    #pragma unroll
    for (int c = 0; c < 5; ++c) {
      int p = (cbase + c) * 16 + lrow;
      float bb1 = b1p[p], bb2 = b2p[p], bb3 = b3p[p];
      #pragma unroll
      for (int r = 0; r < 4; ++r) {
        float v1 = af1[rg][c][r] + bb1;
        float v3 = af3[rg][c][r] + bb3;
        af1[rg][c][r] = v1; af3[rg][c][r] = v3;
        s1 += v1 * v1 + v3 * v3;
        s3 += bb2 * v3;
        s5 += bb2 * v1;
        atomicAdd(&F1s[p], v1);
        atomicAdd(&F3s[p], v3);
      }
    }
  __syncthreads();

  // ---- phase 2: u2i = esumI . w2_p ----
  stage(esumI + base);
  __syncthreads();
  float s4 = 0.f, s6 = 0.f;
  #pragma unroll
  for (int rg = 0; rg < 2; ++rg)
    #pragma unroll
    for (int c = 0; c < 5; ++c) {
      f32x4 u; u[0]=0.f; u[1]=0.f; u[2]=0.f; u[3]=0.f;
      for (int s = 0; s < 16; ++s) {
        bf16x8 a = aload(rg, s);
        bf16x8 bfr = *(const bf16x8*)(w2p + ((size_t)(((cbase + c) * 16 + s) * 64 + lane)) * 8);
        u = __builtin_amdgcn_mfma_f32_16x16x32_bf16(a, bfr, u, 0, 0, 0);
      }
      int p = (cbase + c) * 16 + lrow;
      float bb2 = b2p[p];
      #pragma unroll
      for (int r = 0; r < 4; ++r) { s4 += af1[rg][c][r] * u[r]; s6 += bb2 * u[r]; }
    }
  __syncthreads();

  // ---- phase 3: u2j = esumJ . w2_p ----
  stage(esumJ + base);
  __syncthreads();
  float s2 = 0.f;
  #pragma unroll
  for (int rg = 0; rg < 2; ++rg)
    #pragma unroll
    for (int c = 0; c < 5; ++c) {
      f32x4 u; u[0]=0.f; u[1]=0.f; u[2]=0.f; u[3]=0.f;
      for (int s = 0; s < 16; ++s) {
        bf16x8 a = aload(rg, s);
        bf16x8 bfr = *(const bf16x8*)(w2p + ((size_t)(((cbase + c) * 16 + s) * 64 + lane)) * 8);
        u = __builtin_amdgcn_mfma_f32_16x16x32_bf16(a, bfr, u, 0, 0, 0);
      }
      #pragma unroll
      for (int r = 0; r < 4; ++r) s2 += af3[rg][c][r] * u[r];
    }
  __syncthreads();

  // ---- S7 = sum_p F3s*F1s, then per-block reduce of all 7 scalars ----
  float s7 = 0.f;
  for (int t = tid; t < PPAD; t += 256) s7 += F3s[t] * F1s[t];

  float vals[7] = {s1, s2, s3, s4, s5, s6, s7};
  #pragma unroll
  for (int k = 0; k < 7; ++k) {
    float v = vals[k];
    #pragma unroll
    for (int m = 32; m >= 1; m >>= 1) v += __shfl_xor(v, m, 64);
    if (lane == 0) red[wave][k] = (double)v;
  }
  __syncthreads();
  if (tid == 0) {
    #pragma unroll
    for (int k = 0; k < 7; ++k)
      pnode[(size_t)b * 8 + k] = red[0][k] + red[1][k] + red[2][k] + red[3][k];
  }
}

// ---------------- final combine ----------------
__global__ __launch_bounds__(256) void final_kernel(
    const double* __restrict__ pedge, const double* __restrict__ pnode,
    const float* __restrict__ b2p, const int* __restrict__ seqp,
    float* __restrict__ out)
{
  __shared__ double red[4][9];
  const int tid = threadIdx.x, wave = tid >> 6, lane = tid & 63;
  double vals[9];
  #pragma unroll
  for (int k = 0; k < 9; ++k) vals[k] = 0.0;
  for (int t = tid; t < 5120 * 4; t += 256) vals[0] += pedge[t];
  for (int t = tid; t < 320; t += 256)
    #pragma unroll
    for (int k = 0; k < 7; ++k) vals[1 + k] += pnode[(size_t)t * 8 + k];
  for (int t = tid; t < PPAD; t += 256) { double v = (double)b2p[t]; vals[8] += v * v; }
  #pragma unroll
  for (int k = 0; k < 9; ++k) {
    double v = vals[k];
    #pragma unroll
    for (int m = 32; m >= 1; m >>= 1) v += __shfl_xor(v, m, 64);
    if (lane == 0) red[wave][k] = v;
  }
  __syncthreads();
  if (tid == 0) {
    double a[9];
    #pragma unroll
    for (int k = 0; k < 9; ++k) a[k] = red[0][k] + red[1][k] + red[2][k] + red[3][k];
    double Sa2 = a[0], S1 = a[1], S2 = a[2], S3 = a[3], S4 = a[4], S5 = a[5], S6 = a[6], S7 = a[7], NB2 = a[8];
    const double N = 32.0, TEd = (double)TE;
    double Tf2 = Sa2 + 2.0 * S6 + TEd * NB2;
    double Total = N * S1 + Tf2 - 2.0 * (S2 + N * S3) + 2.0 * (S4 + N * S5) - 2.0 * S7;
    int seq = seqp[0];
    int batch = (seq > 0) ? (BATSEQ / seq) : 1;
    out[0] = (float)(Total / ((double)BATSEQ * (double)PROJ) / (double)batch);
  }
}

extern "C" void kernel_launch(void* const* d_in, const int* in_sizes, int n_in,
                              void* d_out, int out_size, void* d_ws, size_t ws_size,
                              hipStream_t stream)
{
  const float* nodes = (const float*)d_in[0];
  const float* edges = (const float*)d_in[1];
  const int*   seqp  = (const int*)d_in[4];
  const float* W1 = (const float*)d_in[5];
  const float* b1 = (const float*)d_in[6];
  const float* W2 = (const float*)d_in[7];
  const float* b2 = (const float*)d_in[8];
  const float* W3 = (const float*)d_in[9];
  const float* b3 = (const float*)d_in[10];

  char* ws = (char*)d_ws;
  unsigned short* w1p = (unsigned short*)(ws + 0);
  unsigned short* w3p = (unsigned short*)(ws + 327680);
  unsigned short* w2p = (unsigned short*)(ws + 655360);
  float* b1p = (float*)(ws + 983040);
  float* b2p = (float*)(ws + 984320);
  float* b3p = (float*)(ws + 985600);
  float* esumI = (float*)(ws + 1048576);
  float* esumJ = (float*)(ws + 22020096);
  double* pedge = (double*)(ws + 42991616);   // 5120*4 doubles
  double* pnode = (double*)(ws + 43155456);   // 320*8 doubles

  hipMemsetAsync(ws + 1048576, 0, 41943040, stream);  // esumI + esumJ
  prep_kernel<<<1925, 256, 0, stream>>>(W1, b1, W2, b2, W3, b3,
                                        w1p, w2p, w3p, b1p, b2p, b3p);
  edge_kernel<<<TE / 64, 256, 0, stream>>>(edges, w2p, esumI, esumJ, pedge);
  node_kernel<<<320, 256, 0, stream>>>(nodes, esumI, esumJ,
                                       w1p, w2p, w3p, b1p, b2p, b3p, pnode);
  final_kernel<<<1, 256, 0, stream>>>(pedge, pnode, b2p, seqp, (float*)d_out);
}

// Round 2
// 397.640 us; speedup vs baseline: 1.8883x; 1.8883x over previous
//
#include <hip/hip_runtime.h>
#include <hip/hip_bf16.h>
#include <stdint.h>

#define STATE 512
#define PROJ 300
#define PPAD 320
#define BATSEQ 320
#define TE 327680            // 320*1024 edges
#define F3STRIDE 324         // f32 words; 324%32=4 -> banks spread for m-step-4 reads; 324*4%16==0

typedef __bf16 bf16x8 __attribute__((ext_vector_type(8)));
typedef float f32x4 __attribute__((ext_vector_type(4)));

__device__ inline unsigned short f2bf(float x) {
  unsigned u = __builtin_bit_cast(unsigned, x);
  unsigned r = u + 0x7fffu + ((u >> 16) & 1u);   // round-to-nearest-even
  return (unsigned short)(r >> 16);
}

// ---------------- prep: pack W1/W2/W3 into MFMA B-fragment layout (bf16, P padded to 320),
// and pad biases to 320 floats ----------------
__global__ __launch_bounds__(256) void prep_kernel(
    const float* __restrict__ W1, const float* __restrict__ b1,
    const float* __restrict__ W2, const float* __restrict__ b2,
    const float* __restrict__ W3, const float* __restrict__ b3,
    unsigned short* __restrict__ w1p, unsigned short* __restrict__ w2p,
    unsigned short* __restrict__ w3p,
    float* __restrict__ b1p, float* __restrict__ b2p, float* __restrict__ b3p)
{
  int idx = blockIdx.x * 256 + threadIdx.x;
  const int WN = PPAD * STATE;                    // 163840
  if (idx < 3 * WN) {
    int which = idx / WN, r = idx % WN;
    int cs = r / 512, q = r % 512;                // cs = c*16+s
    int lane = q / 8, i = q % 8;
    int c = cs / 16, s = cs % 16;
    int p = c * 16 + (lane & 15);
    int k = s * 32 + (lane >> 4) * 8 + i;
    const float* W = (which == 0) ? W1 : ((which == 1) ? W2 : W3);
    unsigned short* dst = (which == 0) ? w1p : ((which == 1) ? w2p : w3p);
    float v = (p < PROJ) ? W[(size_t)p * STATE + k] : 0.0f;
    dst[r] = f2bf(v);
  } else if (idx < 3 * WN + 3 * PPAD) {
    int r = idx - 3 * WN;
    int which = r / PPAD, p = r % PPAD;
    const float* B = (which == 0) ? b1 : ((which == 1) ? b2 : b3);
    float* dst = (which == 0) ? b1p : ((which == 1) ? b2p : b3p);
    dst[p] = (p < PROJ) ? B[p] : 0.0f;
  }
}

// ---------------- node kernel: one block per b. Computes f1 = W1*n + b1 and
// f3' = W3*n + b3 - b2, writes both as f32 tables [b][row][320], and the
// closed-form  T_b = 32*sum(f1^2 + f3'^2) - 2*sum_p (sum_j f3')(sum_i f1). ----------------
__global__ __launch_bounds__(256, 2) void node_kernel(
    const float* __restrict__ nodes,
    const unsigned short* __restrict__ w1p, const unsigned short* __restrict__ w3p,
    const float* __restrict__ b1p, const float* __restrict__ b2p,
    const float* __restrict__ b3p,
    float* __restrict__ f1t, float* __restrict__ f3t,
    double* __restrict__ pnode)
{
  __shared__ __align__(16) unsigned short tile[32 * 512];   // 32 KiB
  __shared__ float G1[PPAD], G3[PPAD];
  __shared__ double red[4];
  const int tid = threadIdx.x;
  const int wave = tid >> 6, lane = tid & 63;
  const int b = blockIdx.x;
  const float* src = nodes + (size_t)b * 32 * STATE;

  for (int t = tid; t < PPAD; t += 256) { G1[t] = 0.f; G3[t] = 0.f; }

  // stage 32x512 f32 -> bf16 LDS, swizzle: byte ^= (row&7)<<4
  #pragma unroll
  for (int m = 0; m < 16; ++m) {
    int k = wave + 4 * m;
    int row = k >> 1;
    int fc = (k & 1) * 64 + lane;
    f32x4 v = *(const f32x4*)(src + row * STATE + fc * 4);
    unsigned lo = f2bf(v.x) | ((unsigned)f2bf(v.y) << 16);
    unsigned hi = f2bf(v.z) | ((unsigned)f2bf(v.w) << 16);
    unsigned long long pk = (unsigned long long)lo | ((unsigned long long)hi << 32);
    unsigned off = (unsigned)(row * 1024 + fc * 8) ^ (unsigned)((row & 7) << 4);
    *(unsigned long long*)((char*)tile + off) = pk;
  }
  __syncthreads();

  const int lrow = lane & 15, lk = lane >> 4;
  const int cbase = wave * 5;

  f32x4 af1[2][5], af3[2][5];
  #pragma unroll
  for (int rg = 0; rg < 2; ++rg)
    #pragma unroll
    for (int c = 0; c < 5; ++c) {
      af1[rg][c][0]=0.f; af1[rg][c][1]=0.f; af1[rg][c][2]=0.f; af1[rg][c][3]=0.f;
      af3[rg][c][0]=0.f; af3[rg][c][1]=0.f; af3[rg][c][2]=0.f; af3[rg][c][3]=0.f;
    }
  for (int s = 0; s < 16; ++s) {
    bf16x8 a[2];
    #pragma unroll
    for (int rg = 0; rg < 2; ++rg) {
      int row = rg * 16 + lrow;
      unsigned off = (unsigned)(row * 1024 + s * 64 + lk * 16) ^ (unsigned)((row & 7) << 4);
      a[rg] = *(const bf16x8*)((const char*)tile + off);
    }
    #pragma unroll
    for (int c = 0; c < 5; ++c) {
      size_t fo = ((size_t)(((cbase + c) * 16 + s) * 64 + lane)) * 8;
      bf16x8 bf1 = *(const bf16x8*)(w1p + fo);
      bf16x8 bf3 = *(const bf16x8*)(w3p + fo);
      #pragma unroll
      for (int rg = 0; rg < 2; ++rg) {
        af1[rg][c] = __builtin_amdgcn_mfma_f32_16x16x32_bf16(a[rg], bf1, af1[rg][c], 0, 0, 0);
        af3[rg][c] = __builtin_amdgcn_mfma_f32_16x16x32_bf16(a[rg], bf3, af3[rg][c], 0, 0, 0);
      }
    }
  }

  float sq = 0.f;
  #pragma unroll
  for (int rg = 0; rg < 2; ++rg)
    #pragma unroll
    for (int c = 0; c < 5; ++c) {
      int p = (cbase + c) * 16 + lrow;
      float bb1 = b1p[p], bb2 = b2p[p], bb3 = b3p[p];
      #pragma unroll
      for (int r = 0; r < 4; ++r) {
        int m = rg * 16 + lk * 4 + r;           // C/D row = edge of lane>>4 and reg
        float v1 = af1[rg][c][r] + bb1;
        float v3 = af3[rg][c][r] + bb3 - bb2;
        f1t[((size_t)b * 32 + m) * PPAD + p] = v1;
        f3t[((size_t)b * 32 + m) * PPAD + p] = v3;
        sq += v1 * v1 + v3 * v3;
        atomicAdd(&G1[p], v1);
        atomicAdd(&G3[p], v3);
      }
    }
  __syncthreads();

  float s7 = 0.f;
  for (int t = tid; t < PPAD; t += 256) s7 += G3[t] * G1[t];

  float val = 32.f * sq - 2.f * s7;
  #pragma unroll
  for (int m = 32; m >= 1; m >>= 1) val += __shfl_xor(val, m, 64);
  if (lane == 0) red[wave] = (double)val;
  __syncthreads();
  if (tid == 0) pnode[b] = red[0] + red[1] + red[2] + red[3];
}

// ---------------- edge kernel: block = (b, i), 32 contiguous rows (all j).
// Streams edges once, MFMA F2 = W2*e, contracts in-register against
// t = f3'[b][j] - f1[b][i]. Emits one double per block: sum(F2^2 - 2*t*F2). ----------------
__global__ __launch_bounds__(256, 2) void edge_kernel(
    const float* __restrict__ edges, const unsigned short* __restrict__ w2p,
    const float* __restrict__ f1t, const float* __restrict__ f3t,
    double* __restrict__ pedge)
{
  __shared__ __align__(16) unsigned short tile[32 * 512];   // 32 KiB
  __shared__ __align__(16) float f3s[32 * F3STRIDE];        // 40.5 KiB
  __shared__ double redd[4];
  const int tid = threadIdx.x;
  const int wave = tid >> 6, lane = tid & 63;

  // XCD-chunked swizzle: all 32 blocks of one b land on one XCD (10240 % 8 == 0)
  const int orig = blockIdx.x;
  const int wg = (orig & 7) * 1280 + (orig >> 3);
  const int b = wg >> 5, i = wg & 31;
  const float* src = edges + ((size_t)b * 1024 + (size_t)i * 32) * STATE;

  const int lrow = lane & 15, lk = lane >> 4;
  const int cb = wave * 5;

  // stage edges 32x512 f32 -> bf16 LDS (XOR swizzle)
  #pragma unroll
  for (int m = 0; m < 16; ++m) {
    int k = wave + 4 * m;
    int row = k >> 1;
    int fc = (k & 1) * 64 + lane;
    f32x4 v = *(const f32x4*)(src + row * STATE + fc * 4);
    unsigned lo = f2bf(v.x) | ((unsigned)f2bf(v.y) << 16);
    unsigned hi = f2bf(v.z) | ((unsigned)f2bf(v.w) << 16);
    unsigned long long pk = (unsigned long long)lo | ((unsigned long long)hi << 32);
    unsigned off = (unsigned)(row * 1024 + fc * 8) ^ (unsigned)((row & 7) << 4);
    *(unsigned long long*)((char*)tile + off) = pk;
  }
  // stage f3'[b] 32x320 f32 -> LDS stride F3STRIDE
  {
    const float* f3src = f3t + (size_t)b * 32 * PPAD;
    #pragma unroll
    for (int q = 0; q < 10; ++q) {
      int idx = tid + 256 * q;                 // 0..2559
      int row = idx / 80, v4 = idx % 80;
      f32x4 v = *(const f32x4*)(f3src + row * PPAD + v4 * 4);
      *(f32x4*)(f3s + row * F3STRIDE + v4 * 4) = v;
    }
  }
  // f1[b][i] for this lane's 5 p-columns
  float f1v[5];
  {
    const float* f1src = f1t + ((size_t)b * 32 + i) * PPAD;
    #pragma unroll
    for (int c = 0; c < 5; ++c) f1v[c] = f1src[(cb + c) * 16 + lrow];
  }
  __syncthreads();

  // MFMA: 32 rows x 320 cols (wave owns cols cb*16..+80), K=512
  f32x4 acc[2][5];
  #pragma unroll
  for (int rg = 0; rg < 2; ++rg)
    #pragma unroll
    for (int c = 0; c < 5; ++c) { acc[rg][c][0]=0.f; acc[rg][c][1]=0.f; acc[rg][c][2]=0.f; acc[rg][c][3]=0.f; }
  for (int s = 0; s < 16; ++s) {
    bf16x8 a[2];
    #pragma unroll
    for (int rg = 0; rg < 2; ++rg) {
      int row = rg * 16 + lrow;
      unsigned off = (unsigned)(row * 1024 + s * 64 + lk * 16) ^ (unsigned)((row & 7) << 4);
      a[rg] = *(const bf16x8*)((const char*)tile + off);
    }
    #pragma unroll
    for (int c = 0; c < 5; ++c) {
      bf16x8 bfr = *(const bf16x8*)(w2p + ((size_t)(((cb + c) * 16 + s) * 64 + lane)) * 8);
      #pragma unroll
      for (int rg = 0; rg < 2; ++rg)
        acc[rg][c] = __builtin_amdgcn_mfma_f32_16x16x32_bf16(a[rg], bfr, acc[rg][c], 0, 0, 0);
    }
  }

  // epilogue: e = sum(F2^2) - 2*sum((f3'[j] - f1)*F2)
  float e1 = 0.f, e2 = 0.f;
  #pragma unroll
  for (int rg = 0; rg < 2; ++rg)
    #pragma unroll
    for (int c = 0; c < 5; ++c) {
      int p = (cb + c) * 16 + lrow;
      #pragma unroll
      for (int r = 0; r < 4; ++r) {
        int m = rg * 16 + lk * 4 + r;          // j index
        float F2 = acc[rg][c][r];
        float t = f3s[m * F3STRIDE + p] - f1v[c];
        e1 += F2 * F2;
        e2 += t * F2;
      }
    }
  float val = e1 - 2.f * e2;
  #pragma unroll
  for (int m = 32; m >= 1; m >>= 1) val += __shfl_xor(val, m, 64);
  if (lane == 0) redd[wave] = (double)val;
  __syncthreads();
  if (tid == 0) pedge[wg] = redd[0] + redd[1] + redd[2] + redd[3];
}

// ---------------- final combine ----------------
__global__ __launch_bounds__(256) void final_kernel(
    const double* __restrict__ pedge, const double* __restrict__ pnode,
    const int* __restrict__ seqp, float* __restrict__ out)
{
  __shared__ double red[4];
  const int tid = threadIdx.x, wave = tid >> 6, lane = tid & 63;
  double v = 0.0;
  for (int t = tid; t < 10240; t += 256) v += pedge[t];
  for (int t = tid; t < 320; t += 256) v += pnode[t];
  #pragma unroll
  for (int m = 32; m >= 1; m >>= 1) v += __shfl_xor(v, m, 64);
  if (lane == 0) red[wave] = v;
  __syncthreads();
  if (tid == 0) {
    double Total = red[0] + red[1] + red[2] + red[3];
    int seq = seqp[0];
    int batch = (seq > 0) ? (BATSEQ / seq) : 1;
    out[0] = (float)(Total / ((double)BATSEQ * (double)PROJ) / (double)batch);
  }
}

extern "C" void kernel_launch(void* const* d_in, const int* in_sizes, int n_in,
                              void* d_out, int out_size, void* d_ws, size_t ws_size,
                              hipStream_t stream)
{
  const float* nodes = (const float*)d_in[0];
  const float* edges = (const float*)d_in[1];
  const int*   seqp  = (const int*)d_in[4];
  const float* W1 = (const float*)d_in[5];
  const float* b1 = (const float*)d_in[6];
  const float* W2 = (const float*)d_in[7];
  const float* b2 = (const float*)d_in[8];
  const float* W3 = (const float*)d_in[9];
  const float* b3 = (const float*)d_in[10];

  char* ws = (char*)d_ws;
  unsigned short* w1p = (unsigned short*)(ws + 0);
  unsigned short* w3p = (unsigned short*)(ws + 327680);
  unsigned short* w2p = (unsigned short*)(ws + 655360);
  float* b1p = (float*)(ws + 983040);
  float* b2p = (float*)(ws + 984320);
  float* b3p = (float*)(ws + 985600);
  float* f1t = (float*)(ws + 1048576);            // 13,107,200 B
  float* f3t = (float*)(ws + 14155776);           // 13,107,200 B
  double* pedge = (double*)(ws + 27262976);       // 10240 doubles
  double* pnode = (double*)(ws + 27344896);       // 320 doubles

  prep_kernel<<<1925, 256, 0, stream>>>(W1, b1, W2, b2, W3, b3,
                                        w1p, w2p, w3p, b1p, b2p, b3p);
  node_kernel<<<320, 256, 0, stream>>>(nodes, w1p, w3p, b1p, b2p, b3p,
                                       f1t, f3t, pnode);
  edge_kernel<<<10240, 256, 0, stream>>>(edges, w2p, f1t, f3t, pedge);
  final_kernel<<<1, 256, 0, stream>>>(pedge, pnode, seqp, (float*)d_out);
}